// Round 4
// baseline (427.372 us; speedup 1.0000x reference)
//
#include <hip/hip_runtime.h>
#include <hip/hip_bf16.h>

#define B_   32
#define D_   128
#define N_   16384            // H*W
#define K_   32
#define NS   256              // n per sub-tile per block
#define AST_STRIDE 264        // bf16 units; 264*2=528B rows (16B-aligned), even 8dw/bank on b128

// ---- workspace layout (floats) ----
#define WS_WBF  0             // bf16 W[32][128] = -2*scale*log2e*cw  (2048 floats)
#define WS_SC   2048          // scale[k]*log2e (32)
#define WS_C2S  2080          // scale'[k]*||c_k||^2 (32)
#define WS_EP   2112          // Ep[NB][32][128], then AsumP[NB][32] after

typedef __attribute__((ext_vector_type(8))) short bf16x8;
typedef __attribute__((ext_vector_type(4))) float f32x4;

static __device__ inline unsigned int pk2(float lo, float hi) {
    __hip_bfloat162 h = __float22bfloat162_rn(make_float2(lo, hi));
    unsigned int r;
    __builtin_memcpy(&r, &h, 4);
    return r;
}

static __device__ inline bf16x8 pack8(const float* v) {
    union { unsigned int u[4]; bf16x8 f; } r;
    r.u[0] = pk2(v[0], v[1]);
    r.u[1] = pk2(v[2], v[3]);
    r.u[2] = pk2(v[4], v[5]);
    r.u[3] = pk2(v[6], v[7]);
    return r.f;
}

__global__ void prep_kernel(const float* __restrict__ cw,
                            const float* __restrict__ scale,
                            float* __restrict__ ws) {
    const int k = blockIdx.x;     // 32 blocks x 64 lanes
    const int l = threadIdx.x;
    const float sc = scale[k] * 1.44269504088896f;   // fold log2e
    unsigned short* Wbf = (unsigned short*)(ws + WS_WBF);
    float s = 0.f;
#pragma unroll
    for (int i = 0; i < 2; ++i) {
        const int d = l + i * 64;
        const float v = cw[k * D_ + d];
        s += v * v;
        const float w = -2.f * sc * v;
        unsigned int u = __float_as_uint(w);
        u += 0x7fffu + ((u >> 16) & 1u);
        Wbf[k * D_ + d] = (unsigned short)(u >> 16);
    }
#pragma unroll
    for (int o = 32; o > 0; o >>= 1) s += __shfl_down(s, o, 64);
    if (l == 0) {
        ws[WS_SC  + k] = sc;
        ws[WS_C2S + k] = sc * s;
    }
}

template<int NCHUNKT>
__global__ __launch_bounds__(256, 6) void main_kernel(
        const float* __restrict__ X,
        const float* __restrict__ ws_ro,
        float* __restrict__ AsumP,
        float* __restrict__ Ep)
{
    constexpr int CSZT  = N_ / NCHUNKT;
    constexpr int NSUBT = CSZT / NS;

    __shared__ __align__(16) unsigned short AsT[K_ * AST_STRIDE];  // 16896 B

    const int t    = threadIdx.x;
    const int lane = t & 63;
    const int w    = t >> 6;          // wave 0..3
    const int mc   = lane & 15;
    const int q    = lane >> 4;

    const int blk   = blockIdx.x;
    const int b     = blk / NCHUNKT;
    const int chunk = blk % NCHUNKT;
    const int n0    = chunk * CSZT;

    const float* Xb = X + (size_t)b * ((size_t)D_ * N_);

    // ---- persistent codeword A-frags: W[k = kb*16+mc][d = kd*32 + q*8 + j] ----
    const unsigned short* Wbf = (const unsigned short*)(ws_ro + WS_WBF);
    bf16x8 wf[2][4];
#pragma unroll
    for (int kb = 0; kb < 2; ++kb)
#pragma unroll
        for (int kd = 0; kd < 4; ++kd)
            wf[kb][kd] = *(const bf16x8*)&Wbf[(kb * 16 + mc) * D_ + kd * 32 + q * 8];

    // per-lane softmax constants for k = kb*16 + q*4 + r
    float scr[2][4], c2r[2][4];
#pragma unroll
    for (int kb = 0; kb < 2; ++kb)
#pragma unroll
        for (int r = 0; r < 4; ++r) {
            scr[kb][r] = ws_ro[WS_SC  + kb * 16 + q * 4 + r];
            c2r[kb][r] = ws_ro[WS_C2S + kb * 16 + q * 4 + r];
        }

    bf16x8 ones;
#pragma unroll
    for (int i = 0; i < 8; ++i) ones[i] = (short)0x3F80;

    f32x4 accE[2][2] = {{{0.f,0.f,0.f,0.f},{0.f,0.f,0.f,0.f}},
                        {{0.f,0.f,0.f,0.f},{0.f,0.f,0.f,0.f}}};
    f32x4 accO[2]    = {{0.f,0.f,0.f,0.f},{0.f,0.f,0.f,0.f}};

    for (int s = 0; s < NSUBT; ++s) {
        const int ns = n0 + s * NS;

        // ================= phase 1: xc via MFMA + in-register softmax =================
#pragma unroll 1
        for (int cb = 0; cb < 4; ++cb) {
            const int ntl = (w * 4 + cb) * 16;          // local n of this col-block
            const float* xp = Xb + ns + ntl + mc;       // column for this lane

            f32x4 S0 = {0.f,0.f,0.f,0.f};
            f32x4 S1 = {0.f,0.f,0.f,0.f};
            float x2 = 0.f;
#pragma unroll
            for (int kdp = 0; kdp < 2; ++kdp) {
                // batch 16 loads into one vmcnt window for MLP
                float xv[16];
#pragma unroll
                for (int h = 0; h < 2; ++h)
#pragma unroll
                    for (int j = 0; j < 8; ++j)
                        xv[h * 8 + j] =
                            xp[(size_t)((kdp * 2 + h) * 32 + q * 8 + j) * N_];
#pragma unroll
                for (int i = 0; i < 16; ++i) x2 = fmaf(xv[i], xv[i], x2);
#pragma unroll
                for (int h = 0; h < 2; ++h) {
                    const bf16x8 xb = pack8(&xv[h * 8]);
                    const int kd = kdp * 2 + h;
                    S0 = __builtin_amdgcn_mfma_f32_16x16x32_bf16(wf[0][kd], xb, S0, 0, 0, 0);
                    S1 = __builtin_amdgcn_mfma_f32_16x16x32_bf16(wf[1][kd], xb, S1, 0, 0, 0);
                }
            }
            // x2: lane covered 32 of 128 d; sum over the q-groups
            x2 += __shfl_xor(x2, 16, 64);
            x2 += __shfl_xor(x2, 32, 64);

            // sl[k] (already scaled by log2e) for k = {q*4+r, 16+q*4+r}
            float sl[8];
#pragma unroll
            for (int r = 0; r < 4; ++r) {
                sl[r]     = fmaf(scr[0][r], x2, S0[r] + c2r[0][r]);
                sl[4 + r] = fmaf(scr[1][r], x2, S1[r] + c2r[1][r]);
            }
            float m = sl[0];
#pragma unroll
            for (int i = 1; i < 8; ++i) m = fmaxf(m, sl[i]);
            m = fmaxf(m, __shfl_xor(m, 16, 64));
            m = fmaxf(m, __shfl_xor(m, 32, 64));
            float ssum = 0.f;
#pragma unroll
            for (int i = 0; i < 8; ++i) { sl[i] = exp2f(sl[i] - m); ssum += sl[i]; }
            ssum += __shfl_xor(ssum, 16, 64);
            ssum += __shfl_xor(ssum, 32, 64);
            const float inv = 1.f / ssum;

            const int col = ntl + mc;
#pragma unroll
            for (int r = 0; r < 4; ++r) {
                const unsigned int u = pk2(sl[r] * inv, sl[4 + r] * inv);
                AsT[(q * 4 + r) * AST_STRIDE + col]        = (unsigned short)u;
                AsT[(16 + q * 4 + r) * AST_STRIDE + col]   = (unsigned short)(u >> 16);
            }
        }
        __syncthreads();   // AsT complete

        // ================= phase 2: E += A^T . X via MFMA (contracts n) =================
        const int dq = w;
#pragma unroll 2
        for (int ks = 0; ks < NS / 32; ++ks) {
            const int nl = ks * 32 + q * 8;
            const bf16x8 a0 = *(const bf16x8*)&AsT[mc * AST_STRIDE + nl];
            const bf16x8 a1 = *(const bf16x8*)&AsT[(16 + mc) * AST_STRIDE + nl];

            const float* bp = Xb + (size_t)(dq * 32 + mc) * N_ + ns + nl;
            float xr[8];
            *(float4*)&xr[0] = *(const float4*)bp;
            *(float4*)&xr[4] = *(const float4*)(bp + 4);
            const bf16x8 xb0 = pack8(xr);
            const float* bp2 = bp + (size_t)16 * N_;
            float xs[8];
            *(float4*)&xs[0] = *(const float4*)bp2;
            *(float4*)&xs[4] = *(const float4*)(bp2 + 4);
            const bf16x8 xb1 = pack8(xs);

            accE[0][0] = __builtin_amdgcn_mfma_f32_16x16x32_bf16(a0, xb0, accE[0][0], 0, 0, 0);
            accE[0][1] = __builtin_amdgcn_mfma_f32_16x16x32_bf16(a0, xb1, accE[0][1], 0, 0, 0);
            accE[1][0] = __builtin_amdgcn_mfma_f32_16x16x32_bf16(a1, xb0, accE[1][0], 0, 0, 0);
            accE[1][1] = __builtin_amdgcn_mfma_f32_16x16x32_bf16(a1, xb1, accE[1][1], 0, 0, 0);
            if (w == 0) {
                accO[0] = __builtin_amdgcn_mfma_f32_16x16x32_bf16(a0, ones, accO[0], 0, 0, 0);
                accO[1] = __builtin_amdgcn_mfma_f32_16x16x32_bf16(a1, ones, accO[1], 0, 0, 0);
            }
        }
        __syncthreads();   // done reading AsT before next sub-tile overwrites
    }

    // ---- epilogue: per-block partials ----
    float* EpB = Ep + (size_t)blk * (K_ * D_);
#pragma unroll
    for (int kh = 0; kh < 2; ++kh)
#pragma unroll
        for (int ds = 0; ds < 2; ++ds)
#pragma unroll
            for (int r = 0; r < 4; ++r) {
                const int k = kh * 16 + q * 4 + r;
                const int d = w * 32 + ds * 16 + mc;
                EpB[k * D_ + d] = accE[kh][ds][r];
            }
    if (w == 0 && mc == 0) {
#pragma unroll
        for (int kh = 0; kh < 2; ++kh)
#pragma unroll
            for (int r = 0; r < 4; ++r)
                AsumP[blk * K_ + kh * 16 + q * 4 + r] = accO[kh][r];
    }
}

template<int NCHUNKT>
__global__ void finalize_kernel(const float* __restrict__ cw,
                                const float* __restrict__ AsumP,
                                const float* __restrict__ Ep,
                                float* __restrict__ out)
{
    const int idx = blockIdx.x * 256 + threadIdx.x;   // 131072 outputs
    const int d = idx & 127;
    const int k = (idx >> 7) & 31;
    const int b = idx >> 12;
    float s = 0.f, asum = 0.f;
#pragma unroll 8
    for (int c = 0; c < NCHUNKT; ++c) {
        const int blk = b * NCHUNKT + c;
        s    += Ep[(size_t)blk * (K_ * D_) + k * D_ + d];
        asum += AsumP[blk * K_ + k];
    }
    out[idx] = s - asum * cw[k * D_ + d];
}

extern "C" void kernel_launch(void* const* d_in, const int* in_sizes, int n_in,
                              void* d_out, int out_size, void* d_ws, size_t ws_size,
                              hipStream_t stream) {
    const float* X     = (const float*)d_in[0];
    const float* cw    = (const float*)d_in[1];
    const float* scale = (const float*)d_in[2];
    float* out = (float*)d_out;
    float* ws  = (float*)d_ws;

    prep_kernel<<<K_, 64, 0, stream>>>(cw, scale, ws);

    const size_t need64 = (size_t)(WS_EP + 2048 * (K_ * D_ + K_)) * 4;
    const size_t need32 = (size_t)(WS_EP + 1024 * (K_ * D_ + K_)) * 4;
    if (ws_size >= need64) {
        float* Ep    = ws + WS_EP;
        float* AsumP = Ep + (size_t)2048 * (K_ * D_);
        main_kernel<64><<<B_ * 64, 256, 0, stream>>>(X, ws, AsumP, Ep);
        finalize_kernel<64><<<(B_ * K_ * D_) / 256, 256, 0, stream>>>(cw, AsumP, Ep, out);
    } else if (ws_size >= need32) {
        float* Ep    = ws + WS_EP;
        float* AsumP = Ep + (size_t)1024 * (K_ * D_);
        main_kernel<32><<<B_ * 32, 256, 0, stream>>>(X, ws, AsumP, Ep);
        finalize_kernel<32><<<(B_ * K_ * D_) / 256, 256, 0, stream>>>(cw, AsumP, Ep, out);
    } else {
        float* Ep    = ws + WS_EP;
        float* AsumP = Ep + (size_t)512 * (K_ * D_);
        main_kernel<16><<<B_ * 16, 256, 0, stream>>>(X, ws, AsumP, Ep);
        finalize_kernel<16><<<(B_ * K_ * D_) / 256, 256, 0, stream>>>(cw, AsumP, Ep, out);
    }
}